// Round 11
// baseline (333.091 us; speedup 1.0000x reference)
//
#include <hip/hip_runtime.h>
#include <math.h>

#define N_NODES 100000
#define N_EDGES 3200000
#define LO_BITS 7
#define NPB 128                               // nodes per bucket (dst & 127, dst >> 7)
#define NB  ((N_NODES + NPB - 1) / NPB)       // 782 buckets
#define PART_B 512                            // partition blocks
#define CPB (N_EDGES / PART_B)                // 6250 edges per partition block (exact)

typedef unsigned long long u64;
typedef unsigned int u32;
typedef unsigned short u16;

// float <-> bf16 (round-to-nearest-even)
static __device__ inline u16 f2bf(float f) {
    u32 u = __float_as_uint(f);
    return (u16)((u + 0x7FFF + ((u >> 16) & 1)) >> 16);
}
static __device__ inline float bf2f(u16 h) {
    return __uint_as_float((u32)h << 16);
}

// ---------------- stage 1: multisplit into 782 buckets (NO global atomics) ----------

__global__ void hist_k(const int* __restrict__ dst, int* __restrict__ hist_mat) {
    __shared__ int h[NB];
    for (int t = threadIdx.x; t < NB; t += blockDim.x) h[t] = 0;
    __syncthreads();
    int base = blockIdx.x * CPB;
    for (int it = 0; it < (CPB + 255) / 256; it++) {
        int e = base + it * 256 + threadIdx.x;
        if (e < base + CPB) {
            int d = __builtin_nontemporal_load(&dst[e]);
            atomicAdd(&h[d >> LO_BITS], 1);                  // LDS atomic only
        }
    }
    __syncthreads();
    for (int t = threadIdx.x; t < NB; t += blockDim.x)
        hist_mat[blockIdx.x * NB + t] = h[t];
}

__global__ void colscan_k(int* __restrict__ hist_mat, int* __restrict__ tot) {
    __shared__ int s[PART_B];
    int bin = blockIdx.x, t = threadIdx.x;
    int v = hist_mat[t * NB + bin];
    s[t] = v;
    __syncthreads();
#pragma unroll
    for (int off = 1; off < PART_B; off <<= 1) {
        int u = (t >= off) ? s[t - off] : 0;
        __syncthreads();
        s[t] += u;
        __syncthreads();
    }
    hist_mat[t * NB + bin] = s[t] - v;        // exclusive within column
    if (t == PART_B - 1) tot[bin] = s[t];
}

__global__ void base_k(const int* __restrict__ tot, int* __restrict__ bbase) {
    __shared__ int s[1024];
    int t = threadIdx.x;
    int v = (t < NB) ? tot[t] : 0;
    s[t] = v;
    __syncthreads();
#pragma unroll
    for (int off = 1; off < 1024; off <<= 1) {
        int u = (t >= off) ? s[t - off] : 0;
        __syncthreads();
        s[t] += u;
        __syncthreads();
    }
    if (t < NB) bbase[t] = s[t] - v;
    if (t == 0) bbase[NB] = N_EDGES;
}

__global__ void part_k(const int* __restrict__ src, const int* __restrict__ dst,
                       const float* __restrict__ w, const int* __restrict__ hist_mat,
                       const int* __restrict__ bbase, u64* __restrict__ ebuf) {
    __shared__ int cur[NB];
    for (int t = threadIdx.x; t < NB; t += blockDim.x)
        cur[t] = bbase[t] + hist_mat[blockIdx.x * NB + t];
    __syncthreads();
    int base = blockIdx.x * CPB;
    for (int it = 0; it < (CPB + 255) / 256; it++) {
        int e = base + it * 256 + threadIdx.x;
        if (e < base + CPB) {
            int d = __builtin_nontemporal_load(&dst[e]);
            int sv = __builtin_nontemporal_load(&src[e]);
            float wv = __builtin_nontemporal_load(&w[e]);
            int p = atomicAdd(&cur[d >> LO_BITS], 1);       // LDS atomic only
            u32 hi = ((u32)sv << LO_BITS) | (u32)(d & (NPB - 1));
            ebuf[p] = ((u64)hi << 32) | (u64)__float_as_uint(wv);
        }
    }
}

// ---------------- stage 2: per-bucket CSR-ization + degree (one block per bucket) ----
__global__ void __launch_bounds__(512) csr_deg_k(
        const u64* __restrict__ ebuf, const int* __restrict__ bbase,
        int* __restrict__ row_ptr, float* __restrict__ dinv,
        u64* __restrict__ pedge) {
    __shared__ int   cnt[NPB];
    __shared__ float wsum[NPB];
    __shared__ int   sc[NPB];
    __shared__ int   cur[NPB];
    int b = blockIdx.x, t = threadIdx.x;
    if (t < NPB) { cnt[t] = 0; wsum[t] = 0.0f; }
    __syncthreads();
    int j0 = bbase[b], j1 = bbase[b + 1];
    for (int j = j0 + t; j < j1; j += 512) {
        u64 pe = __builtin_nontemporal_load(&ebuf[j]);
        int lo = (int)((u32)(pe >> 32) & (NPB - 1));
        atomicAdd(&cnt[lo], 1);                              // LDS atomic
        atomicAdd(&wsum[lo], __uint_as_float((u32)pe));      // LDS atomic
    }
    __syncthreads();
    // exclusive scan of cnt[0..NPB)
    int v = (t < NPB) ? cnt[t] : 0;
    if (t < NPB) sc[t] = v;
    __syncthreads();
#pragma unroll
    for (int off = 1; off < NPB; off <<= 1) {
        int u = (t < NPB && t >= off) ? sc[t - off] : 0;
        __syncthreads();
        if (t < NPB) sc[t] += u;
        __syncthreads();
    }
    int node = b * NPB + t;
    if (t < NPB) {
        int excl = sc[t] - v;
        cur[t] = j0 + excl;
        if (node < N_NODES) {
            row_ptr[node] = j0 + excl;
            dinv[node] = rsqrtf(1.0f + wsum[t]);             // self-loop weight 1
        }
    }
    if (b == NB - 1 && t == 0) row_ptr[N_NODES] = N_EDGES;
    __syncthreads();
    // pass 2: node-grouped scatter within the bucket's contiguous range (L2-hot window)
    for (int j = j0 + t; j < j1; j += 512) {
        u64 pe = __builtin_nontemporal_load(&ebuf[j]);
        u32 hi = (u32)(pe >> 32);
        int lo = (int)(hi & (NPB - 1));
        int p = atomicAdd(&cur[lo], 1);                      // LDS atomic
        pedge[p] = ((u64)(hi >> LO_BITS) << 32) | (u64)(u32)pe;   // (src, raw w)
    }
}

// ---------------- dense / gather kernels ----------------

// g1 = bf16( (x @ W1) * dinv[node] )  — 3.2 MB table, kept L2-resident
__global__ void gemm1(const float* __restrict__ x, const float* __restrict__ W1,
                      const float* __restrict__ dinv, u16* __restrict__ g1b) {
    __shared__ float sW[64 * 16];
    for (int t = threadIdx.x; t < 64 * 16; t += blockDim.x) sW[t] = W1[t];
    __syncthreads();
    int gid = blockIdx.x * blockDim.x + threadIdx.x;
    int node = gid >> 4, c = gid & 15;
    if (node >= N_NODES) return;
    const float4* xr = (const float4*)(x + node * 64);
    float acc = 0.0f;
#pragma unroll
    for (int q = 0; q < 16; q++) {
        float4 xv = xr[q];
        acc += xv.x * sW[(q * 4 + 0) * 16 + c];
        acc += xv.y * sW[(q * 4 + 1) * 16 + c];
        acc += xv.z * sW[(q * 4 + 2) * 16 + c];
        acc += xv.w * sW[(q * 4 + 3) * 16 + c];
    }
    g1b[node * 16 + c] = f2bf(acc * dinv[node]);
}

// conv1 gather: one wave per node. Stage 64 edges with ONE coalesced nt load,
// distribute via shuffle, then 8 fully-unrolled INDEPENDENT g1b loads per lane
// (8 edge-groups x 8 feat-pair lanes; u32 load = 2 bf16 feats). fp32 accum.
__global__ void gather1(const int* __restrict__ row_ptr, const u64* __restrict__ pedge,
                        const float* __restrict__ dinv, const u32* __restrict__ g1w,
                        const float* __restrict__ b1, const float* __restrict__ W2,
                        float* __restrict__ y2) {
    int gid = blockIdx.x * blockDim.x + threadIdx.x;
    int node = gid >> 6;
    if (node >= N_NODES) return;
    int lane = threadIdx.x & 63;
    int c2 = lane & 7;          // feature pair [0,8)
    int eg = lane >> 3;         // edge slot    [0,8)
    int j0 = row_ptr[node], j1 = row_ptr[node + 1];
    float a0 = 0.0f, a1 = 0.0f;
    for (int base = j0; base < j1; base += 64) {
        int idx = base + lane;
        u64 se = (idx < j1) ? __builtin_nontemporal_load(&pedge[idx]) : 0ULL;
#pragma unroll
        for (int k = 0; k < 8; k++) {
            u64 pe = __shfl(se, k * 8 + eg, 64);   // edge (base + k*8 + eg)
            int s = (int)(pe >> 32);
            float wr = __uint_as_float((u32)pe);   // 0 for padded slots
            u32 g2 = g1w[s * 8 + c2];
            a0 += bf2f((u16)g2) * wr;
            a1 += bf2f((u16)(g2 >> 16)) * wr;
        }
    }
    // reduce across the 8 edge slots
    a0 += __shfl_xor(a0, 8, 64);  a1 += __shfl_xor(a1, 8, 64);
    a0 += __shfl_xor(a0, 16, 64); a1 += __shfl_xor(a1, 16, 64);
    a0 += __shfl_xor(a0, 32, 64); a1 += __shfl_xor(a1, 32, 64);
    // self-loop (g1 = h1*dinv)
    u32 gs = g1w[node * 8 + c2];
    a0 += bf2f((u16)gs);
    a1 += bf2f((u16)(gs >> 16));
    float di = dinv[node];
    int c0 = c2 * 2, c1 = c0 + 1;
    float v0 = a0 * di + b1[c0]; v0 = v0 > 0.0f ? v0 : 0.0f;
    float v1 = a1 * di + b1[c1]; v1 = v1 > 0.0f ? v1 : 0.0f;
    // fused gemm2 over the 8 feat-pair lanes
    float p0 = v0 * W2[c0 * 2]     + v1 * W2[c1 * 2];
    float p1 = v0 * W2[c0 * 2 + 1] + v1 * W2[c1 * 2 + 1];
    p0 += __shfl_xor(p0, 1, 64); p1 += __shfl_xor(p1, 1, 64);
    p0 += __shfl_xor(p0, 2, 64); p1 += __shfl_xor(p1, 2, 64);
    p0 += __shfl_xor(p0, 4, 64); p1 += __shfl_xor(p1, 4, 64);
    if (lane == 0) {
        y2[node * 2]     = p0 * di;               // pre-scale for layer 2
        y2[node * 2 + 1] = p1 * di;
    }
}

// conv2 gather: one wave per node, staged-shuffle, 32 edges x 2 comps per pass
__global__ void gather2(const int* __restrict__ row_ptr, const u64* __restrict__ pedge,
                        const float* __restrict__ dinv, const float* __restrict__ y2,
                        const float* __restrict__ b2, const float* __restrict__ lin_w,
                        const float* __restrict__ lin_b, float* __restrict__ out) {
    int gid = blockIdx.x * blockDim.x + threadIdx.x;
    int i = gid >> 6;
    if (i >= N_NODES) return;
    int lane = threadIdx.x & 63;
    int k = lane & 1;           // component
    int el = lane >> 1;         // edge lane [0,32)
    int j0 = row_ptr[i], j1 = row_ptr[i + 1];
    float a = 0.0f;
    for (int base = j0; base < j1; base += 64) {
        int idx = base + lane;
        u64 se = (idx < j1) ? __builtin_nontemporal_load(&pedge[idx]) : 0ULL;
#pragma unroll
        for (int k2 = 0; k2 < 2; k2++) {
            u64 pe = __shfl(se, k2 * 32 + el, 64);
            int s = (int)(pe >> 32);
            float wr = __uint_as_float((u32)pe);
            a += y2[s * 2 + k] * wr;
        }
    }
    // reduce across the 32 edge lanes (lane bits 1..5)
    a += __shfl_xor(a, 2, 64);
    a += __shfl_xor(a, 4, 64);
    a += __shfl_xor(a, 8, 64);
    a += __shfl_xor(a, 16, 64);
    a += __shfl_xor(a, 32, 64);
    float ao = __shfl_xor(a, 1, 64);             // other component's sum
    if (lane == 0) {
        float di = dinv[i];
        float y0 = y2[i * 2], y1 = y2[i * 2 + 1];
        float x20 = (a + y0) * di + b2[0];
        float x21 = (ao + y1) * di + b2[1];
        out[N_NODES + i * 2]     = x20;
        out[N_NODES + i * 2 + 1] = x21;
        float r0 = x20 > 0.0f ? x20 : 0.0f;
        float r1 = x21 > 0.0f ? x21 : 0.0f;
        float z = r0 * lin_w[0] + r1 * lin_w[1] + lin_b[0];
        out[i] = 1.0f / (1.0f + expf(-z));
    }
}

extern "C" void kernel_launch(void* const* d_in, const int* in_sizes, int n_in,
                              void* d_out, int out_size, void* d_ws, size_t ws_size,
                              hipStream_t stream) {
    const float* x     = (const float*)d_in[0];
    const int*   ei    = (const int*)d_in[1];   // [2, E] flattened
    const float* ew    = (const float*)d_in[2];
    const float* W1    = (const float*)d_in[3];
    const float* b1    = (const float*)d_in[4];
    const float* W2    = (const float*)d_in[5];
    const float* b2    = (const float*)d_in[6];
    const float* lin_w = (const float*)d_in[7];
    const float* lin_b = (const float*)d_in[8];
    float* out = (float*)d_out;

    const int* src = ei;
    const int* dst = ei + N_EDGES;

    // ---- workspace carve-up (g1b/y2 alias the dead ebuf region, DISJOINTLY) ----
    char* w8 = (char*)d_ws;
    size_t off = 0;
    auto take = [&](size_t bytes) { char* p = w8 + off; off += (bytes + 15) & ~((size_t)15); return (void*)p; };
    u64*   ebuf     = (u64*)  take((size_t)N_EDGES * 8);       // 25.6 MB (dead after csr_deg_k)
    u64*   pedge    = (u64*)  take((size_t)N_EDGES * 8);       // 25.6 MB
    int*   hist_mat = (int*)  take((size_t)PART_B * NB * 4);   // ~1.6 MB
    int*   tot      = (int*)  take((size_t)NB * 4);
    int*   bbase    = (int*)  take((size_t)(NB + 1) * 4);
    int*   row_ptr  = (int*)  take((size_t)(N_NODES + 1) * 4);
    float* dinv     = (float*)take((size_t)N_NODES * 4);
    u16*   g1b      = (u16*)ebuf;                              // bytes [0, 3.2MB)
    u32*   g1w      = (u32*)ebuf;                              // u32 view of the same table
    float* y2       = (float*)ebuf + (size_t)8 * N_NODES;      // bytes [3.2MB, 4.0MB)

    const int B = 256;

    // stage 1: multisplit to 782 buckets (zero global atomics)
    hist_k<<<PART_B, B, 0, stream>>>(dst, hist_mat);
    colscan_k<<<NB, PART_B, 0, stream>>>(hist_mat, tot);
    base_k<<<1, 1024, 0, stream>>>(tot, bbase);
    part_k<<<PART_B, B, 0, stream>>>(src, dst, ew, hist_mat, bbase, ebuf);

    // stage 2: per-bucket CSR + degree (zero global atomics)
    csr_deg_k<<<NB, 512, 0, stream>>>(ebuf, bbase, row_ptr, dinv, pedge);

    // layer 1 (norm algebraically folded: g1 pre-scaled by dinv[src]; bf16 table)
    gemm1<<<(16 * N_NODES + B - 1) / B, B, 0, stream>>>(x, W1, dinv, g1b);
    gather1<<<(64 * N_NODES + B - 1) / B, B, 0, stream>>>(row_ptr, pedge, dinv, g1w, b1, W2, y2);

    // layer 2 + head
    gather2<<<(64 * N_NODES + B - 1) / B, B, 0, stream>>>(row_ptr, pedge, dinv, y2, b2,
                                                         lin_w, lin_b, out);
}

// Round 12
// 310.600 us; speedup vs baseline: 1.0724x; 1.0724x over previous
//
#include <hip/hip_runtime.h>
#include <math.h>

#define N_NODES 100000
#define N_EDGES 3200000
#define LO_BITS 7
#define NPB 128                               // nodes per bucket (dst & 127, dst >> 7)
#define NB  ((N_NODES + NPB - 1) / NPB)       // 782 buckets
#define PART_B 128                            // partition blocks (1024 threads each)
#define PART_T 1024
#define CPB (N_EDGES / PART_B)                // 25000 edges per partition block (exact)

typedef unsigned long long u64;
typedef unsigned int u32;
typedef unsigned short u16;

// float <-> bf16 (round-to-nearest-even)
static __device__ inline u16 f2bf(float f) {
    u32 u = __float_as_uint(f);
    return (u16)((u + 0x7FFF + ((u >> 16) & 1)) >> 16);
}
static __device__ inline float bf2f(u16 h) {
    return __uint_as_float((u32)h << 16);
}

// ---------------- stage 1: multisplit into 782 buckets (NO global atomics) ----------

__global__ void __launch_bounds__(PART_T) hist_k(const int* __restrict__ dst,
                                                 int* __restrict__ hist_mat) {
    __shared__ int h[NB];
    for (int t = threadIdx.x; t < NB; t += blockDim.x) h[t] = 0;
    __syncthreads();
    int base = blockIdx.x * CPB;
    for (int it = 0; it < (CPB + PART_T - 1) / PART_T; it++) {
        int e = base + it * PART_T + threadIdx.x;
        if (e < base + CPB) {
            int d = dst[e];                        // keep cached: part_k re-reads dst
            atomicAdd(&h[d >> LO_BITS], 1);        // LDS atomic only
        }
    }
    __syncthreads();
    for (int t = threadIdx.x; t < NB; t += blockDim.x)
        hist_mat[blockIdx.x * NB + t] = h[t];
}

// column-wise exclusive scan over the 128 partition blocks: one block per bin
__global__ void colscan_k(int* __restrict__ hist_mat, int* __restrict__ tot) {
    __shared__ int s[PART_B];
    int bin = blockIdx.x, t = threadIdx.x;
    int v = hist_mat[t * NB + bin];
    s[t] = v;
    __syncthreads();
#pragma unroll
    for (int off = 1; off < PART_B; off <<= 1) {
        int u = (t >= off) ? s[t - off] : 0;
        __syncthreads();
        s[t] += u;
        __syncthreads();
    }
    hist_mat[t * NB + bin] = s[t] - v;        // exclusive within column
    if (t == PART_B - 1) tot[bin] = s[t];
}

__global__ void base_k(const int* __restrict__ tot, int* __restrict__ bbase) {
    __shared__ int s[1024];
    int t = threadIdx.x;
    int v = (t < NB) ? tot[t] : 0;
    s[t] = v;
    __syncthreads();
#pragma unroll
    for (int off = 1; off < 1024; off <<= 1) {
        int u = (t >= off) ? s[t - off] : 0;
        __syncthreads();
        s[t] += u;
        __syncthreads();
    }
    if (t < NB) bbase[t] = s[t] - v;
    if (t == 0) bbase[NB] = N_EDGES;
}

__global__ void __launch_bounds__(PART_T) part_k(
        const int* __restrict__ src, const int* __restrict__ dst,
        const float* __restrict__ w, const int* __restrict__ hist_mat,
        const int* __restrict__ bbase, u64* __restrict__ ebuf) {
    __shared__ int cur[NB];
    for (int t = threadIdx.x; t < NB; t += blockDim.x)
        cur[t] = bbase[t] + hist_mat[blockIdx.x * NB + t];
    __syncthreads();
    int base = blockIdx.x * CPB;
    for (int it = 0; it < (CPB + PART_T - 1) / PART_T; it++) {
        int e = base + it * PART_T + threadIdx.x;
        if (e < base + CPB) {
            int d = __builtin_nontemporal_load(&dst[e]);     // last use of these streams
            int sv = __builtin_nontemporal_load(&src[e]);
            float wv = __builtin_nontemporal_load(&w[e]);
            int p = atomicAdd(&cur[d >> LO_BITS], 1);        // LDS atomic only
            u32 hi = ((u32)sv << LO_BITS) | (u32)(d & (NPB - 1));
            ebuf[p] = ((u64)hi << 32) | (u64)__float_as_uint(wv);
        }
    }
}

// ---------------- stage 2: per-bucket CSR-ization + degree (one block per bucket) ----
__global__ void __launch_bounds__(512) csr_deg_k(
        const u64* __restrict__ ebuf, const int* __restrict__ bbase,
        int* __restrict__ row_ptr, float* __restrict__ dinv,
        u64* __restrict__ pedge) {
    __shared__ int   cnt[NPB];
    __shared__ float wsum[NPB];
    __shared__ int   sc[NPB];
    __shared__ int   cur[NPB];
    int b = blockIdx.x, t = threadIdx.x;
    if (t < NPB) { cnt[t] = 0; wsum[t] = 0.0f; }
    __syncthreads();
    int j0 = bbase[b], j1 = bbase[b + 1];
    for (int j = j0 + t; j < j1; j += 512) {
        u64 pe = ebuf[j];                                    // L2-resident: plain load
        int lo = (int)((u32)(pe >> 32) & (NPB - 1));
        atomicAdd(&cnt[lo], 1);                              // LDS atomic
        atomicAdd(&wsum[lo], __uint_as_float((u32)pe));      // LDS atomic
    }
    __syncthreads();
    // exclusive scan of cnt[0..NPB)
    int v = (t < NPB) ? cnt[t] : 0;
    if (t < NPB) sc[t] = v;
    __syncthreads();
#pragma unroll
    for (int off = 1; off < NPB; off <<= 1) {
        int u = (t < NPB && t >= off) ? sc[t - off] : 0;
        __syncthreads();
        if (t < NPB) sc[t] += u;
        __syncthreads();
    }
    int node = b * NPB + t;
    if (t < NPB) {
        int excl = sc[t] - v;
        cur[t] = j0 + excl;
        if (node < N_NODES) {
            row_ptr[node] = j0 + excl;
            dinv[node] = rsqrtf(1.0f + wsum[t]);             // self-loop weight 1
        }
    }
    if (b == NB - 1 && t == 0) row_ptr[N_NODES] = N_EDGES;
    __syncthreads();
    // pass 2: node-grouped scatter within the bucket's contiguous (L2-hot) window
    for (int j = j0 + t; j < j1; j += 512) {
        u64 pe = ebuf[j];
        u32 hi = (u32)(pe >> 32);
        int lo = (int)(hi & (NPB - 1));
        int p = atomicAdd(&cur[lo], 1);                      // LDS atomic
        pedge[p] = ((u64)(hi >> LO_BITS) << 32) | (u64)(u32)pe;   // (src, raw w)
    }
}

// ---------------- dense / gather kernels ----------------

// g1 = bf16( (x @ W1) * dinv[node] ) — x rows staged once through LDS (no 16x re-read)
__global__ void __launch_bounds__(256) gemm1(
        const float* __restrict__ x, const float* __restrict__ W1,
        const float* __restrict__ dinv, u16* __restrict__ g1b) {
    __shared__ float sW[64 * 16];
    __shared__ float xs[16][68];              // 16 nodes/block, +4 pad vs 64
    for (int t = threadIdx.x; t < 64 * 16; t += blockDim.x) sW[t] = W1[t];
    int nbase = blockIdx.x * 16;              // 6250 blocks x 16 nodes = exact
    // stage 16 rows coalesced: 256 threads x 1 float4 each
    {
        int q = threadIdx.x;                  // [0,256): node q>>4, float4 (q&15)
        const float4 v = ((const float4*)(x + (size_t)nbase * 64))[q];
        int n = q >> 4, f4 = q & 15;
        xs[n][f4 * 4 + 0] = v.x;
        xs[n][f4 * 4 + 1] = v.y;
        xs[n][f4 * 4 + 2] = v.z;
        xs[n][f4 * 4 + 3] = v.w;
    }
    __syncthreads();
    int n = threadIdx.x >> 4, c = threadIdx.x & 15;
    int node = nbase + n;
    float acc = 0.0f;
#pragma unroll
    for (int k = 0; k < 64; k++) acc += xs[n][k] * sW[k * 16 + c];
    g1b[node * 16 + c] = f2bf(acc * dinv[node]);
}

// conv1 gather: one wave per node, staged-shuffle, 8 independent g1 loads in flight
__global__ void gather1(const int* __restrict__ row_ptr, const u64* __restrict__ pedge,
                        const float* __restrict__ dinv, const u32* __restrict__ g1w,
                        const float* __restrict__ b1, const float* __restrict__ W2,
                        float* __restrict__ y2) {
    int gid = blockIdx.x * blockDim.x + threadIdx.x;
    int node = gid >> 6;
    if (node >= N_NODES) return;
    int lane = threadIdx.x & 63;
    int c2 = lane & 7;          // feature pair [0,8)
    int eg = lane >> 3;         // edge slot    [0,8)
    int j0 = row_ptr[node], j1 = row_ptr[node + 1];
    float a0 = 0.0f, a1 = 0.0f;
    for (int base = j0; base < j1; base += 64) {
        int idx = base + lane;
        u64 se = (idx < j1) ? __builtin_nontemporal_load(&pedge[idx]) : 0ULL;
#pragma unroll
        for (int k = 0; k < 8; k++) {
            u64 pe = __shfl(se, k * 8 + eg, 64);   // edge (base + k*8 + eg)
            int s = (int)(pe >> 32);
            float wr = __uint_as_float((u32)pe);   // 0 for padded slots
            u32 g2 = g1w[s * 8 + c2];
            a0 += bf2f((u16)g2) * wr;
            a1 += bf2f((u16)(g2 >> 16)) * wr;
        }
    }
    // reduce across the 8 edge slots
    a0 += __shfl_xor(a0, 8, 64);  a1 += __shfl_xor(a1, 8, 64);
    a0 += __shfl_xor(a0, 16, 64); a1 += __shfl_xor(a1, 16, 64);
    a0 += __shfl_xor(a0, 32, 64); a1 += __shfl_xor(a1, 32, 64);
    // self-loop (g1 = h1*dinv)
    u32 gs = g1w[node * 8 + c2];
    a0 += bf2f((u16)gs);
    a1 += bf2f((u16)(gs >> 16));
    float di = dinv[node];
    int c0 = c2 * 2, c1 = c0 + 1;
    float v0 = a0 * di + b1[c0]; v0 = v0 > 0.0f ? v0 : 0.0f;
    float v1 = a1 * di + b1[c1]; v1 = v1 > 0.0f ? v1 : 0.0f;
    // fused gemm2 over the 8 feat-pair lanes
    float p0 = v0 * W2[c0 * 2]     + v1 * W2[c1 * 2];
    float p1 = v0 * W2[c0 * 2 + 1] + v1 * W2[c1 * 2 + 1];
    p0 += __shfl_xor(p0, 1, 64); p1 += __shfl_xor(p1, 1, 64);
    p0 += __shfl_xor(p0, 2, 64); p1 += __shfl_xor(p1, 2, 64);
    p0 += __shfl_xor(p0, 4, 64); p1 += __shfl_xor(p1, 4, 64);
    if (lane == 0) {
        y2[node * 2]     = p0 * di;               // pre-scale for layer 2
        y2[node * 2 + 1] = p1 * di;
    }
}

// conv2 gather: one wave per node, staged-shuffle, 32 edges x 2 comps per pass
__global__ void gather2(const int* __restrict__ row_ptr, const u64* __restrict__ pedge,
                        const float* __restrict__ dinv, const float* __restrict__ y2,
                        const float* __restrict__ b2, const float* __restrict__ lin_w,
                        const float* __restrict__ lin_b, float* __restrict__ out) {
    int gid = blockIdx.x * blockDim.x + threadIdx.x;
    int i = gid >> 6;
    if (i >= N_NODES) return;
    int lane = threadIdx.x & 63;
    int k = lane & 1;           // component
    int el = lane >> 1;         // edge lane [0,32)
    int j0 = row_ptr[i], j1 = row_ptr[i + 1];
    float a = 0.0f;
    for (int base = j0; base < j1; base += 64) {
        int idx = base + lane;
        u64 se = (idx < j1) ? __builtin_nontemporal_load(&pedge[idx]) : 0ULL;
#pragma unroll
        for (int k2 = 0; k2 < 2; k2++) {
            u64 pe = __shfl(se, k2 * 32 + el, 64);
            int s = (int)(pe >> 32);
            float wr = __uint_as_float((u32)pe);
            a += y2[s * 2 + k] * wr;
        }
    }
    // reduce across the 32 edge lanes (lane bits 1..5)
    a += __shfl_xor(a, 2, 64);
    a += __shfl_xor(a, 4, 64);
    a += __shfl_xor(a, 8, 64);
    a += __shfl_xor(a, 16, 64);
    a += __shfl_xor(a, 32, 64);
    float ao = __shfl_xor(a, 1, 64);             // other component's sum
    if (lane == 0) {
        float di = dinv[i];
        float y0 = y2[i * 2], y1 = y2[i * 2 + 1];
        float x20 = (a + y0) * di + b2[0];
        float x21 = (ao + y1) * di + b2[1];
        out[N_NODES + i * 2]     = x20;
        out[N_NODES + i * 2 + 1] = x21;
        float r0 = x20 > 0.0f ? x20 : 0.0f;
        float r1 = x21 > 0.0f ? x21 : 0.0f;
        float z = r0 * lin_w[0] + r1 * lin_w[1] + lin_b[0];
        out[i] = 1.0f / (1.0f + expf(-z));
    }
}

extern "C" void kernel_launch(void* const* d_in, const int* in_sizes, int n_in,
                              void* d_out, int out_size, void* d_ws, size_t ws_size,
                              hipStream_t stream) {
    const float* x     = (const float*)d_in[0];
    const int*   ei    = (const int*)d_in[1];   // [2, E] flattened
    const float* ew    = (const float*)d_in[2];
    const float* W1    = (const float*)d_in[3];
    const float* b1    = (const float*)d_in[4];
    const float* W2    = (const float*)d_in[5];
    const float* b2    = (const float*)d_in[6];
    const float* lin_w = (const float*)d_in[7];
    const float* lin_b = (const float*)d_in[8];
    float* out = (float*)d_out;

    const int* src = ei;
    const int* dst = ei + N_EDGES;

    // ---- workspace carve-up (g1b/y2 alias the dead ebuf region, DISJOINTLY) ----
    char* w8 = (char*)d_ws;
    size_t off = 0;
    auto take = [&](size_t bytes) { char* p = w8 + off; off += (bytes + 15) & ~((size_t)15); return (void*)p; };
    u64*   ebuf     = (u64*)  take((size_t)N_EDGES * 8);       // 25.6 MB (dead after csr_deg_k)
    u64*   pedge    = (u64*)  take((size_t)N_EDGES * 8);       // 25.6 MB
    int*   hist_mat = (int*)  take((size_t)PART_B * NB * 4);   // ~400 KB
    int*   tot      = (int*)  take((size_t)NB * 4);
    int*   bbase    = (int*)  take((size_t)(NB + 1) * 4);
    int*   row_ptr  = (int*)  take((size_t)(N_NODES + 1) * 4);
    float* dinv     = (float*)take((size_t)N_NODES * 4);
    u16*   g1b      = (u16*)ebuf;                              // bytes [0, 3.2MB)
    u32*   g1w      = (u32*)ebuf;                              // u32 view of the same table
    float* y2       = (float*)ebuf + (size_t)8 * N_NODES;      // bytes [3.2MB, 4.0MB)

    const int B = 256;

    // stage 1: multisplit to 782 buckets (zero global atomics)
    hist_k<<<PART_B, PART_T, 0, stream>>>(dst, hist_mat);
    colscan_k<<<NB, PART_B, 0, stream>>>(hist_mat, tot);
    base_k<<<1, 1024, 0, stream>>>(tot, bbase);
    part_k<<<PART_B, PART_T, 0, stream>>>(src, dst, ew, hist_mat, bbase, ebuf);

    // stage 2: per-bucket CSR + degree (zero global atomics)
    csr_deg_k<<<NB, 512, 0, stream>>>(ebuf, bbase, row_ptr, dinv, pedge);

    // layer 1 (norm algebraically folded: g1 pre-scaled by dinv[src]; bf16 table)
    gemm1<<<N_NODES / 16, B, 0, stream>>>(x, W1, dinv, g1b);
    gather1<<<(64 * N_NODES + B - 1) / B, B, 0, stream>>>(row_ptr, pedge, dinv, g1w, b1, W2, y2);

    // layer 2 + head
    gather2<<<(64 * N_NODES + B - 1) / B, B, 0, stream>>>(row_ptr, pedge, dinv, y2, b2,
                                                         lin_w, lin_b, out);
}

// Round 13
// 300.628 us; speedup vs baseline: 1.1080x; 1.0332x over previous
//
#include <hip/hip_runtime.h>
#include <math.h>

#define N_NODES 100000
#define N_EDGES 3200000
#define LO_BITS 7
#define NPB 128                               // nodes per bucket (dst & 127, dst >> 7)
#define NB  ((N_NODES + NPB - 1) / NPB)       // 782 buckets
#define PART_B 256                            // partition blocks (1024 threads each)
#define PART_T 1024
#define CPB (N_EDGES / PART_B)                // 12500 edges per partition block (exact)

typedef unsigned long long u64;
typedef unsigned int u32;
typedef unsigned short u16;

// float <-> bf16 (round-to-nearest-even)
static __device__ inline u16 f2bf(float f) {
    u32 u = __float_as_uint(f);
    return (u16)((u + 0x7FFF + ((u >> 16) & 1)) >> 16);
}
static __device__ inline float bf2f(u16 h) {
    return __uint_as_float((u32)h << 16);
}

// ---------------- stage 1: multisplit into 782 buckets (NO global atomics) ----------

__global__ void __launch_bounds__(PART_T) hist_k(const int* __restrict__ dst,
                                                 int* __restrict__ hist_mat) {
    __shared__ int h[NB];
    for (int t = threadIdx.x; t < NB; t += blockDim.x) h[t] = 0;
    __syncthreads();
    int base = blockIdx.x * CPB;
    for (int it = 0; it < (CPB + PART_T - 1) / PART_T; it++) {
        int e = base + it * PART_T + threadIdx.x;
        if (e < base + CPB) {
            int d = dst[e];                        // keep cached: part_k re-reads dst
            atomicAdd(&h[d >> LO_BITS], 1);        // LDS atomic only
        }
    }
    __syncthreads();
    for (int t = threadIdx.x; t < NB; t += blockDim.x)
        hist_mat[blockIdx.x * NB + t] = h[t];
}

// column-wise exclusive scan over the 256 partition blocks: one block per bin
__global__ void __launch_bounds__(PART_B) colscan_k(int* __restrict__ hist_mat,
                                                    int* __restrict__ tot) {
    __shared__ int s[PART_B];
    int bin = blockIdx.x, t = threadIdx.x;
    int v = hist_mat[t * NB + bin];
    s[t] = v;
    __syncthreads();
#pragma unroll
    for (int off = 1; off < PART_B; off <<= 1) {
        int u = (t >= off) ? s[t - off] : 0;
        __syncthreads();
        s[t] += u;
        __syncthreads();
    }
    hist_mat[t * NB + bin] = s[t] - v;        // exclusive within column
    if (t == PART_B - 1) tot[bin] = s[t];
}

__global__ void base_k(const int* __restrict__ tot, int* __restrict__ bbase) {
    __shared__ int s[1024];
    int t = threadIdx.x;
    int v = (t < NB) ? tot[t] : 0;
    s[t] = v;
    __syncthreads();
#pragma unroll
    for (int off = 1; off < 1024; off <<= 1) {
        int u = (t >= off) ? s[t - off] : 0;
        __syncthreads();
        s[t] += u;
        __syncthreads();
    }
    if (t < NB) bbase[t] = s[t] - v;
    if (t == 0) bbase[NB] = N_EDGES;
}

__global__ void __launch_bounds__(PART_T) part_k(
        const int* __restrict__ src, const int* __restrict__ dst,
        const float* __restrict__ w, const int* __restrict__ hist_mat,
        const int* __restrict__ bbase, u64* __restrict__ ebuf) {
    __shared__ int cur[NB];
    for (int t = threadIdx.x; t < NB; t += blockDim.x)
        cur[t] = bbase[t] + hist_mat[blockIdx.x * NB + t];
    __syncthreads();
    int base = blockIdx.x * CPB;
    for (int it = 0; it < (CPB + PART_T - 1) / PART_T; it++) {
        int e = base + it * PART_T + threadIdx.x;
        if (e < base + CPB) {
            int d = __builtin_nontemporal_load(&dst[e]);     // last use of these streams
            int sv = __builtin_nontemporal_load(&src[e]);
            float wv = __builtin_nontemporal_load(&w[e]);
            int p = atomicAdd(&cur[d >> LO_BITS], 1);        // LDS atomic only
            u32 hi = ((u32)sv << LO_BITS) | (u32)(d & (NPB - 1));
            ebuf[p] = ((u64)hi << 32) | (u64)__float_as_uint(wv);
        }
    }
}

// ---------------- stage 2: per-bucket CSR-ization + degree (one block per bucket) ----
__global__ void __launch_bounds__(512) csr_deg_k(
        const u64* __restrict__ ebuf, const int* __restrict__ bbase,
        int* __restrict__ row_ptr, float* __restrict__ dinv,
        u64* __restrict__ pedge) {
    __shared__ int   cnt[NPB];
    __shared__ float wsum[NPB];
    __shared__ int   sc[NPB];
    __shared__ int   cur[NPB];
    int b = blockIdx.x, t = threadIdx.x;
    if (t < NPB) { cnt[t] = 0; wsum[t] = 0.0f; }
    __syncthreads();
    int j0 = bbase[b], j1 = bbase[b + 1];
    for (int j = j0 + t; j < j1; j += 512) {
        u64 pe = ebuf[j];                                    // L2-resident: plain load
        int lo = (int)((u32)(pe >> 32) & (NPB - 1));
        atomicAdd(&cnt[lo], 1);                              // LDS atomic
        atomicAdd(&wsum[lo], __uint_as_float((u32)pe));      // LDS atomic
    }
    __syncthreads();
    // exclusive scan of cnt[0..NPB)
    int v = (t < NPB) ? cnt[t] : 0;
    if (t < NPB) sc[t] = v;
    __syncthreads();
#pragma unroll
    for (int off = 1; off < NPB; off <<= 1) {
        int u = (t < NPB && t >= off) ? sc[t - off] : 0;
        __syncthreads();
        if (t < NPB) sc[t] += u;
        __syncthreads();
    }
    int node = b * NPB + t;
    if (t < NPB) {
        int excl = sc[t] - v;
        cur[t] = j0 + excl;
        if (node < N_NODES) {
            row_ptr[node] = j0 + excl;
            dinv[node] = rsqrtf(1.0f + wsum[t]);             // self-loop weight 1
        }
    }
    if (b == NB - 1 && t == 0) row_ptr[N_NODES] = N_EDGES;
    __syncthreads();
    // pass 2: node-grouped scatter within the bucket's contiguous (L2-hot) window
    for (int j = j0 + t; j < j1; j += 512) {
        u64 pe = ebuf[j];
        u32 hi = (u32)(pe >> 32);
        int lo = (int)(hi & (NPB - 1));
        int p = atomicAdd(&cur[lo], 1);                      // LDS atomic
        pedge[p] = ((u64)(hi >> LO_BITS) << 32) | (u64)(u32)pe;   // (src, raw w)
    }
}

// ---------------- dense / gather kernels ----------------

// g1 = bf16( (x @ W1) * dinv[node] ) — x rows staged once through LDS (no 16x re-read)
__global__ void __launch_bounds__(256) gemm1(
        const float* __restrict__ x, const float* __restrict__ W1,
        const float* __restrict__ dinv, u16* __restrict__ g1b) {
    __shared__ float sW[64 * 16];
    __shared__ float xs[16][68];              // 16 nodes/block, +4 pad vs 64
    for (int t = threadIdx.x; t < 64 * 16; t += blockDim.x) sW[t] = W1[t];
    int nbase = blockIdx.x * 16;              // 6250 blocks x 16 nodes = exact
    // stage 16 rows coalesced: 256 threads x 1 float4 each
    {
        int q = threadIdx.x;                  // [0,256): node q>>4, float4 (q&15)
        const float4 v = ((const float4*)(x + (size_t)nbase * 64))[q];
        int n = q >> 4, f4 = q & 15;
        xs[n][f4 * 4 + 0] = v.x;
        xs[n][f4 * 4 + 1] = v.y;
        xs[n][f4 * 4 + 2] = v.z;
        xs[n][f4 * 4 + 3] = v.w;
    }
    __syncthreads();
    int n = threadIdx.x >> 4, c = threadIdx.x & 15;
    int node = nbase + n;
    float acc = 0.0f;
#pragma unroll
    for (int k = 0; k < 64; k++) acc += xs[n][k] * sW[k * 16 + c];
    g1b[node * 16 + c] = f2bf(acc * dinv[node]);
}

// conv1 gather: one wave per node, staged-shuffle, 8 independent g1 loads in flight
__global__ void gather1(const int* __restrict__ row_ptr, const u64* __restrict__ pedge,
                        const float* __restrict__ dinv, const u32* __restrict__ g1w,
                        const float* __restrict__ b1, const float* __restrict__ W2,
                        float* __restrict__ y2) {
    int gid = blockIdx.x * blockDim.x + threadIdx.x;
    int node = gid >> 6;
    if (node >= N_NODES) return;
    int lane = threadIdx.x & 63;
    int c2 = lane & 7;          // feature pair [0,8)
    int eg = lane >> 3;         // edge slot    [0,8)
    int j0 = row_ptr[node], j1 = row_ptr[node + 1];
    float a0 = 0.0f, a1 = 0.0f;
    for (int base = j0; base < j1; base += 64) {
        int idx = base + lane;
        u64 se = (idx < j1) ? __builtin_nontemporal_load(&pedge[idx]) : 0ULL;
#pragma unroll
        for (int k = 0; k < 8; k++) {
            u64 pe = __shfl(se, k * 8 + eg, 64);   // edge (base + k*8 + eg)
            int s = (int)(pe >> 32);
            float wr = __uint_as_float((u32)pe);   // 0 for padded slots
            u32 g2 = g1w[s * 8 + c2];
            a0 += bf2f((u16)g2) * wr;
            a1 += bf2f((u16)(g2 >> 16)) * wr;
        }
    }
    // reduce across the 8 edge slots
    a0 += __shfl_xor(a0, 8, 64);  a1 += __shfl_xor(a1, 8, 64);
    a0 += __shfl_xor(a0, 16, 64); a1 += __shfl_xor(a1, 16, 64);
    a0 += __shfl_xor(a0, 32, 64); a1 += __shfl_xor(a1, 32, 64);
    // self-loop (g1 = h1*dinv)
    u32 gs = g1w[node * 8 + c2];
    a0 += bf2f((u16)gs);
    a1 += bf2f((u16)(gs >> 16));
    float di = dinv[node];
    int c0 = c2 * 2, c1 = c0 + 1;
    float v0 = a0 * di + b1[c0]; v0 = v0 > 0.0f ? v0 : 0.0f;
    float v1 = a1 * di + b1[c1]; v1 = v1 > 0.0f ? v1 : 0.0f;
    // fused gemm2 over the 8 feat-pair lanes
    float p0 = v0 * W2[c0 * 2]     + v1 * W2[c1 * 2];
    float p1 = v0 * W2[c0 * 2 + 1] + v1 * W2[c1 * 2 + 1];
    p0 += __shfl_xor(p0, 1, 64); p1 += __shfl_xor(p1, 1, 64);
    p0 += __shfl_xor(p0, 2, 64); p1 += __shfl_xor(p1, 2, 64);
    p0 += __shfl_xor(p0, 4, 64); p1 += __shfl_xor(p1, 4, 64);
    if (lane == 0) {
        y2[node * 2]     = p0 * di;               // pre-scale for layer 2
        y2[node * 2 + 1] = p1 * di;
    }
}

// conv2 gather: one wave per node, staged-shuffle, 32 edges x 2 comps per pass
__global__ void gather2(const int* __restrict__ row_ptr, const u64* __restrict__ pedge,
                        const float* __restrict__ dinv, const float* __restrict__ y2,
                        const float* __restrict__ b2, const float* __restrict__ lin_w,
                        const float* __restrict__ lin_b, float* __restrict__ out) {
    int gid = blockIdx.x * blockDim.x + threadIdx.x;
    int i = gid >> 6;
    if (i >= N_NODES) return;
    int lane = threadIdx.x & 63;
    int k = lane & 1;           // component
    int el = lane >> 1;         // edge lane [0,32)
    int j0 = row_ptr[i], j1 = row_ptr[i + 1];
    float a = 0.0f;
    for (int base = j0; base < j1; base += 64) {
        int idx = base + lane;
        u64 se = (idx < j1) ? __builtin_nontemporal_load(&pedge[idx]) : 0ULL;
#pragma unroll
        for (int k2 = 0; k2 < 2; k2++) {
            u64 pe = __shfl(se, k2 * 32 + el, 64);
            int s = (int)(pe >> 32);
            float wr = __uint_as_float((u32)pe);
            a += y2[s * 2 + k] * wr;
        }
    }
    // reduce across the 32 edge lanes (lane bits 1..5)
    a += __shfl_xor(a, 2, 64);
    a += __shfl_xor(a, 4, 64);
    a += __shfl_xor(a, 8, 64);
    a += __shfl_xor(a, 16, 64);
    a += __shfl_xor(a, 32, 64);
    float ao = __shfl_xor(a, 1, 64);             // other component's sum
    if (lane == 0) {
        float di = dinv[i];
        float y0 = y2[i * 2], y1 = y2[i * 2 + 1];
        float x20 = (a + y0) * di + b2[0];
        float x21 = (ao + y1) * di + b2[1];
        out[N_NODES + i * 2]     = x20;
        out[N_NODES + i * 2 + 1] = x21;
        float r0 = x20 > 0.0f ? x20 : 0.0f;
        float r1 = x21 > 0.0f ? x21 : 0.0f;
        float z = r0 * lin_w[0] + r1 * lin_w[1] + lin_b[0];
        out[i] = 1.0f / (1.0f + expf(-z));
    }
}

extern "C" void kernel_launch(void* const* d_in, const int* in_sizes, int n_in,
                              void* d_out, int out_size, void* d_ws, size_t ws_size,
                              hipStream_t stream) {
    const float* x     = (const float*)d_in[0];
    const int*   ei    = (const int*)d_in[1];   // [2, E] flattened
    const float* ew    = (const float*)d_in[2];
    const float* W1    = (const float*)d_in[3];
    const float* b1    = (const float*)d_in[4];
    const float* W2    = (const float*)d_in[5];
    const float* b2    = (const float*)d_in[6];
    const float* lin_w = (const float*)d_in[7];
    const float* lin_b = (const float*)d_in[8];
    float* out = (float*)d_out;

    const int* src = ei;
    const int* dst = ei + N_EDGES;

    // ---- workspace carve-up (g1b/y2 alias the dead ebuf region, DISJOINTLY) ----
    char* w8 = (char*)d_ws;
    size_t off = 0;
    auto take = [&](size_t bytes) { char* p = w8 + off; off += (bytes + 15) & ~((size_t)15); return (void*)p; };
    u64*   ebuf     = (u64*)  take((size_t)N_EDGES * 8);       // 25.6 MB (dead after csr_deg_k)
    u64*   pedge    = (u64*)  take((size_t)N_EDGES * 8);       // 25.6 MB
    int*   hist_mat = (int*)  take((size_t)PART_B * NB * 4);   // ~800 KB
    int*   tot      = (int*)  take((size_t)NB * 4);
    int*   bbase    = (int*)  take((size_t)(NB + 1) * 4);
    int*   row_ptr  = (int*)  take((size_t)(N_NODES + 1) * 4);
    float* dinv     = (float*)take((size_t)N_NODES * 4);
    u16*   g1b      = (u16*)ebuf;                              // bytes [0, 3.2MB)
    u32*   g1w      = (u32*)ebuf;                              // u32 view of the same table
    float* y2       = (float*)ebuf + (size_t)8 * N_NODES;      // bytes [3.2MB, 4.0MB)

    const int B = 256;

    // stage 1: multisplit to 782 buckets (zero global atomics)
    hist_k<<<PART_B, PART_T, 0, stream>>>(dst, hist_mat);
    colscan_k<<<NB, PART_B, 0, stream>>>(hist_mat, tot);
    base_k<<<1, 1024, 0, stream>>>(tot, bbase);
    part_k<<<PART_B, PART_T, 0, stream>>>(src, dst, ew, hist_mat, bbase, ebuf);

    // stage 2: per-bucket CSR + degree (zero global atomics)
    csr_deg_k<<<NB, 512, 0, stream>>>(ebuf, bbase, row_ptr, dinv, pedge);

    // layer 1 (norm algebraically folded: g1 pre-scaled by dinv[src]; bf16 table)
    gemm1<<<N_NODES / 16, B, 0, stream>>>(x, W1, dinv, g1b);
    gather1<<<(64 * N_NODES + B - 1) / B, B, 0, stream>>>(row_ptr, pedge, dinv, g1w, b1, W2, y2);

    // layer 2 + head
    gather2<<<(64 * N_NODES + B - 1) / B, B, 0, stream>>>(row_ptr, pedge, dinv, y2, b2,
                                                         lin_w, lin_b, out);
}

// Round 14
// 261.937 us; speedup vs baseline: 1.2716x; 1.1477x over previous
//
#include <hip/hip_runtime.h>
#include <math.h>

#define N_NODES 100000
#define N_EDGES 3200000
#define LO_BITS 7
#define NPB 128                               // nodes per bucket (dst & 127, dst >> 7)
#define NB  ((N_NODES + NPB - 1) / NPB)       // 782 buckets
#define PART_B 512                            // partition blocks
#define PART_T 1024
#define CPB (N_EDGES / PART_B)                // 6250 edges per partition block (exact)

typedef unsigned long long u64;
typedef unsigned int u32;
typedef unsigned short u16;

// float <-> bf16 (round-to-nearest-even)
static __device__ inline u16 f2bf(float f) {
    u32 u = __float_as_uint(f);
    return (u16)((u + 0x7FFF + ((u >> 16) & 1)) >> 16);
}
static __device__ inline float bf2f(u16 h) {
    return __uint_as_float((u32)h << 16);
}

// ---------------- stage 1: multisplit into 782 buckets (NO global atomics) ----------

__global__ void __launch_bounds__(PART_T) hist_k(const int* __restrict__ dst,
                                                 int* __restrict__ hist_mat) {
    __shared__ int h[NB];
    for (int t = threadIdx.x; t < NB; t += blockDim.x) h[t] = 0;
    __syncthreads();
    int base = blockIdx.x * CPB;
    for (int it = 0; it < (CPB + PART_T - 1) / PART_T; it++) {
        int e = base + it * PART_T + threadIdx.x;
        if (e < base + CPB) {
            int d = dst[e];                        // keep cached: part_k re-reads dst
            atomicAdd(&h[d >> LO_BITS], 1);        // LDS atomic only
        }
    }
    __syncthreads();
    for (int t = threadIdx.x; t < NB; t += blockDim.x)
        hist_mat[blockIdx.x * NB + t] = h[t];
}

// column-wise exclusive scan over the 512 partition blocks: one block per bin
__global__ void __launch_bounds__(PART_B) colscan_k(int* __restrict__ hist_mat,
                                                    int* __restrict__ tot) {
    __shared__ int s[PART_B];
    int bin = blockIdx.x, t = threadIdx.x;
    int v = hist_mat[t * NB + bin];
    s[t] = v;
    __syncthreads();
#pragma unroll
    for (int off = 1; off < PART_B; off <<= 1) {
        int u = (t >= off) ? s[t - off] : 0;
        __syncthreads();
        s[t] += u;
        __syncthreads();
    }
    hist_mat[t * NB + bin] = s[t] - v;        // exclusive within column
    if (t == PART_B - 1) tot[bin] = s[t];
}

__global__ void base_k(const int* __restrict__ tot, int* __restrict__ bbase) {
    __shared__ int s[1024];
    int t = threadIdx.x;
    int v = (t < NB) ? tot[t] : 0;
    s[t] = v;
    __syncthreads();
#pragma unroll
    for (int off = 1; off < 1024; off <<= 1) {
        int u = (t >= off) ? s[t - off] : 0;
        __syncthreads();
        s[t] += u;
        __syncthreads();
    }
    if (t < NB) bbase[t] = s[t] - v;
    if (t == 0) bbase[NB] = N_EDGES;
}

// LDS-staged sorted partition: block-local counting sort, then run-coalesced output.
// Packed staging word: [63:47] src (17b) | [46:30] dst (17b) | [29:0] w bits [31:2].
__global__ void __launch_bounds__(PART_T) part_k(
        const int* __restrict__ src, const int* __restrict__ dst,
        const float* __restrict__ w, const int* __restrict__ hist_mat,
        const int* __restrict__ bbase, u64* __restrict__ ebuf) {
    __shared__ u64 sorted[CPB];               // 50.0 KB
    __shared__ int s[PART_T];                 // 4 KB (hist + scan temp)
    __shared__ int cur[NB];                   // 3.1 KB (cursor; starts at lscan)
    __shared__ int gofs[NB];                  // 3.1 KB
    int t = threadIdx.x;
    int base = blockIdx.x * CPB;
    // phase A: block-local histogram
    s[t] = 0;
    __syncthreads();
#pragma unroll
    for (int it = 0; it < (CPB + PART_T - 1) / PART_T; it++) {
        int e = base + it * PART_T + t;
        if (e < base + CPB) atomicAdd(&s[dst[e] >> LO_BITS], 1);
    }
    __syncthreads();
    // exclusive scan s[0..NB) (Hillis-Steele over 1024 slots; NB=782 < 1024)
    int v = s[t];
    __syncthreads();
#pragma unroll
    for (int off = 1; off < PART_T; off <<= 1) {
        int u = (t >= off) ? s[t - off] : 0;
        __syncthreads();
        s[t] += u;
        __syncthreads();
    }
    if (t < NB) {
        int lscan = s[t] - v;                 // block-local exclusive offset
        cur[t] = lscan;
        gofs[t] = bbase[t] + hist_mat[blockIdx.x * NB + t] - lscan;
    }
    __syncthreads();
    // phase B: scatter into LDS in bin-sorted order
#pragma unroll
    for (int it = 0; it < (CPB + PART_T - 1) / PART_T; it++) {
        int e = base + it * PART_T + t;
        if (e < base + CPB) {
            int d = dst[e];
            int sv = __builtin_nontemporal_load(&src[e]);
            u32 wv = __float_as_uint(__builtin_nontemporal_load(&w[e]));
            int pos = atomicAdd(&cur[d >> LO_BITS], 1);   // LDS atomic
            sorted[pos] = ((u64)(u32)sv << 47) | ((u64)(u32)d << 30) | (u64)(wv >> 2);
        }
    }
    __syncthreads();
    // phase C: stream out — consecutive lanes share runs, addresses monotonic
    for (int p = t; p < CPB; p += PART_T) {
        u64 pk = sorted[p];
        int sv = (int)(pk >> 47);
        int d  = (int)((pk >> 30) & 0x1FFFF);
        u32 wv = ((u32)pk & 0x3FFFFFFF) << 2;
        u32 hi = ((u32)sv << LO_BITS) | (u32)(d & (NPB - 1));
        ebuf[gofs[d >> LO_BITS] + p] = ((u64)hi << 32) | (u64)wv;
    }
}

// ---------------- stage 2: per-bucket CSR-ization + degree (one block per bucket) ----
__global__ void __launch_bounds__(512) csr_deg_k(
        const u64* __restrict__ ebuf, const int* __restrict__ bbase,
        int* __restrict__ row_ptr, float* __restrict__ dinv,
        u64* __restrict__ pedge) {
    __shared__ int   cnt[NPB];
    __shared__ float wsum[NPB];
    __shared__ int   sc[NPB];
    __shared__ int   cur[NPB];
    int b = blockIdx.x, t = threadIdx.x;
    if (t < NPB) { cnt[t] = 0; wsum[t] = 0.0f; }
    __syncthreads();
    int j0 = bbase[b], j1 = bbase[b + 1];
    for (int j = j0 + t; j < j1; j += 512) {
        u64 pe = ebuf[j];                                    // L2-resident: plain load
        int lo = (int)((u32)(pe >> 32) & (NPB - 1));
        atomicAdd(&cnt[lo], 1);                              // LDS atomic
        atomicAdd(&wsum[lo], __uint_as_float((u32)pe));      // LDS atomic
    }
    __syncthreads();
    // exclusive scan of cnt[0..NPB)
    int v = (t < NPB) ? cnt[t] : 0;
    if (t < NPB) sc[t] = v;
    __syncthreads();
#pragma unroll
    for (int off = 1; off < NPB; off <<= 1) {
        int u = (t < NPB && t >= off) ? sc[t - off] : 0;
        __syncthreads();
        if (t < NPB) sc[t] += u;
        __syncthreads();
    }
    int node = b * NPB + t;
    if (t < NPB) {
        int excl = sc[t] - v;
        cur[t] = j0 + excl;
        if (node < N_NODES) {
            row_ptr[node] = j0 + excl;
            dinv[node] = rsqrtf(1.0f + wsum[t]);             // self-loop weight 1
        }
    }
    if (b == NB - 1 && t == 0) row_ptr[N_NODES] = N_EDGES;
    __syncthreads();
    // pass 2: node-grouped scatter within the bucket's contiguous (L2-hot) window
    for (int j = j0 + t; j < j1; j += 512) {
        u64 pe = ebuf[j];
        u32 hi = (u32)(pe >> 32);
        int lo = (int)(hi & (NPB - 1));
        int p = atomicAdd(&cur[lo], 1);                      // LDS atomic
        pedge[p] = ((u64)(hi >> LO_BITS) << 32) | (u64)(u32)pe;   // (src, raw w)
    }
}

// ---------------- dense / gather kernels ----------------

// g1 = bf16( (x @ W1) * dinv[node] ) — x rows staged once through LDS (no 16x re-read)
__global__ void __launch_bounds__(256) gemm1(
        const float* __restrict__ x, const float* __restrict__ W1,
        const float* __restrict__ dinv, u16* __restrict__ g1b) {
    __shared__ float sW[64 * 16];
    __shared__ float xs[16][68];              // 16 nodes/block, +4 pad vs 64
    for (int t = threadIdx.x; t < 64 * 16; t += blockDim.x) sW[t] = W1[t];
    int nbase = blockIdx.x * 16;              // 6250 blocks x 16 nodes = exact
    // stage 16 rows coalesced: 256 threads x 1 float4 each
    {
        int q = threadIdx.x;                  // [0,256): node q>>4, float4 (q&15)
        const float4 v = ((const float4*)(x + (size_t)nbase * 64))[q];
        int n = q >> 4, f4 = q & 15;
        xs[n][f4 * 4 + 0] = v.x;
        xs[n][f4 * 4 + 1] = v.y;
        xs[n][f4 * 4 + 2] = v.z;
        xs[n][f4 * 4 + 3] = v.w;
    }
    __syncthreads();
    int n = threadIdx.x >> 4, c = threadIdx.x & 15;
    int node = nbase + n;
    float acc = 0.0f;
#pragma unroll
    for (int k = 0; k < 64; k++) acc += xs[n][k] * sW[k * 16 + c];
    g1b[node * 16 + c] = f2bf(acc * dinv[node]);
}

// conv1 gather: one wave per node, staged-shuffle, 8 independent g1 loads in flight
__global__ void gather1(const int* __restrict__ row_ptr, const u64* __restrict__ pedge,
                        const float* __restrict__ dinv, const u32* __restrict__ g1w,
                        const float* __restrict__ b1, const float* __restrict__ W2,
                        float* __restrict__ y2) {
    int gid = blockIdx.x * blockDim.x + threadIdx.x;
    int node = gid >> 6;
    if (node >= N_NODES) return;
    int lane = threadIdx.x & 63;
    int c2 = lane & 7;          // feature pair [0,8)
    int eg = lane >> 3;         // edge slot    [0,8)
    int j0 = row_ptr[node], j1 = row_ptr[node + 1];
    float a0 = 0.0f, a1 = 0.0f;
    for (int base = j0; base < j1; base += 64) {
        int idx = base + lane;
        u64 se = (idx < j1) ? __builtin_nontemporal_load(&pedge[idx]) : 0ULL;
#pragma unroll
        for (int k = 0; k < 8; k++) {
            u64 pe = __shfl(se, k * 8 + eg, 64);   // edge (base + k*8 + eg)
            int s = (int)(pe >> 32);
            float wr = __uint_as_float((u32)pe);   // 0 for padded slots
            u32 g2 = g1w[s * 8 + c2];
            a0 += bf2f((u16)g2) * wr;
            a1 += bf2f((u16)(g2 >> 16)) * wr;
        }
    }
    // reduce across the 8 edge slots
    a0 += __shfl_xor(a0, 8, 64);  a1 += __shfl_xor(a1, 8, 64);
    a0 += __shfl_xor(a0, 16, 64); a1 += __shfl_xor(a1, 16, 64);
    a0 += __shfl_xor(a0, 32, 64); a1 += __shfl_xor(a1, 32, 64);
    // self-loop (g1 = h1*dinv)
    u32 gs = g1w[node * 8 + c2];
    a0 += bf2f((u16)gs);
    a1 += bf2f((u16)(gs >> 16));
    float di = dinv[node];
    int c0 = c2 * 2, c1 = c0 + 1;
    float v0 = a0 * di + b1[c0]; v0 = v0 > 0.0f ? v0 : 0.0f;
    float v1 = a1 * di + b1[c1]; v1 = v1 > 0.0f ? v1 : 0.0f;
    // fused gemm2 over the 8 feat-pair lanes
    float p0 = v0 * W2[c0 * 2]     + v1 * W2[c1 * 2];
    float p1 = v0 * W2[c0 * 2 + 1] + v1 * W2[c1 * 2 + 1];
    p0 += __shfl_xor(p0, 1, 64); p1 += __shfl_xor(p1, 1, 64);
    p0 += __shfl_xor(p0, 2, 64); p1 += __shfl_xor(p1, 2, 64);
    p0 += __shfl_xor(p0, 4, 64); p1 += __shfl_xor(p1, 4, 64);
    if (lane == 0) {
        y2[node * 2]     = p0 * di;               // pre-scale for layer 2
        y2[node * 2 + 1] = p1 * di;
    }
}

// conv2 gather: one wave per node, staged-shuffle, 32 edges x 2 comps per pass
__global__ void gather2(const int* __restrict__ row_ptr, const u64* __restrict__ pedge,
                        const float* __restrict__ dinv, const float* __restrict__ y2,
                        const float* __restrict__ b2, const float* __restrict__ lin_w,
                        const float* __restrict__ lin_b, float* __restrict__ out) {
    int gid = blockIdx.x * blockDim.x + threadIdx.x;
    int i = gid >> 6;
    if (i >= N_NODES) return;
    int lane = threadIdx.x & 63;
    int k = lane & 1;           // component
    int el = lane >> 1;         // edge lane [0,32)
    int j0 = row_ptr[i], j1 = row_ptr[i + 1];
    float a = 0.0f;
    for (int base = j0; base < j1; base += 64) {
        int idx = base + lane;
        u64 se = (idx < j1) ? __builtin_nontemporal_load(&pedge[idx]) : 0ULL;
#pragma unroll
        for (int k2 = 0; k2 < 2; k2++) {
            u64 pe = __shfl(se, k2 * 32 + el, 64);
            int s = (int)(pe >> 32);
            float wr = __uint_as_float((u32)pe);
            a += y2[s * 2 + k] * wr;
        }
    }
    // reduce across the 32 edge lanes (lane bits 1..5)
    a += __shfl_xor(a, 2, 64);
    a += __shfl_xor(a, 4, 64);
    a += __shfl_xor(a, 8, 64);
    a += __shfl_xor(a, 16, 64);
    a += __shfl_xor(a, 32, 64);
    float ao = __shfl_xor(a, 1, 64);             // other component's sum
    if (lane == 0) {
        float di = dinv[i];
        float y0 = y2[i * 2], y1 = y2[i * 2 + 1];
        float x20 = (a + y0) * di + b2[0];
        float x21 = (ao + y1) * di + b2[1];
        out[N_NODES + i * 2]     = x20;
        out[N_NODES + i * 2 + 1] = x21;
        float r0 = x20 > 0.0f ? x20 : 0.0f;
        float r1 = x21 > 0.0f ? x21 : 0.0f;
        float z = r0 * lin_w[0] + r1 * lin_w[1] + lin_b[0];
        out[i] = 1.0f / (1.0f + expf(-z));
    }
}

extern "C" void kernel_launch(void* const* d_in, const int* in_sizes, int n_in,
                              void* d_out, int out_size, void* d_ws, size_t ws_size,
                              hipStream_t stream) {
    const float* x     = (const float*)d_in[0];
    const int*   ei    = (const int*)d_in[1];   // [2, E] flattened
    const float* ew    = (const float*)d_in[2];
    const float* W1    = (const float*)d_in[3];
    const float* b1    = (const float*)d_in[4];
    const float* W2    = (const float*)d_in[5];
    const float* b2    = (const float*)d_in[6];
    const float* lin_w = (const float*)d_in[7];
    const float* lin_b = (const float*)d_in[8];
    float* out = (float*)d_out;

    const int* src = ei;
    const int* dst = ei + N_EDGES;

    // ---- workspace carve-up (g1b/y2 alias the dead ebuf region, DISJOINTLY) ----
    char* w8 = (char*)d_ws;
    size_t off = 0;
    auto take = [&](size_t bytes) { char* p = w8 + off; off += (bytes + 15) & ~((size_t)15); return (void*)p; };
    u64*   ebuf     = (u64*)  take((size_t)N_EDGES * 8);       // 25.6 MB (dead after csr_deg_k)
    u64*   pedge    = (u64*)  take((size_t)N_EDGES * 8);       // 25.6 MB
    int*   hist_mat = (int*)  take((size_t)PART_B * NB * 4);   // ~1.6 MB
    int*   tot      = (int*)  take((size_t)NB * 4);
    int*   bbase    = (int*)  take((size_t)(NB + 1) * 4);
    int*   row_ptr  = (int*)  take((size_t)(N_NODES + 1) * 4);
    float* dinv     = (float*)take((size_t)N_NODES * 4);
    u16*   g1b      = (u16*)ebuf;                              // bytes [0, 3.2MB)
    u32*   g1w      = (u32*)ebuf;                              // u32 view of the same table
    float* y2       = (float*)ebuf + (size_t)8 * N_NODES;      // bytes [3.2MB, 4.0MB)

    const int B = 256;

    // stage 1: multisplit to 782 buckets (zero global atomics; LDS-sorted writes)
    hist_k<<<PART_B, PART_T, 0, stream>>>(dst, hist_mat);
    colscan_k<<<NB, PART_B, 0, stream>>>(hist_mat, tot);
    base_k<<<1, 1024, 0, stream>>>(tot, bbase);
    part_k<<<PART_B, PART_T, 0, stream>>>(src, dst, ew, hist_mat, bbase, ebuf);

    // stage 2: per-bucket CSR + degree (zero global atomics)
    csr_deg_k<<<NB, 512, 0, stream>>>(ebuf, bbase, row_ptr, dinv, pedge);

    // layer 1 (norm algebraically folded: g1 pre-scaled by dinv[src]; bf16 table)
    gemm1<<<N_NODES / 16, B, 0, stream>>>(x, W1, dinv, g1b);
    gather1<<<(64 * N_NODES + B - 1) / B, B, 0, stream>>>(row_ptr, pedge, dinv, g1w, b1, W2, y2);

    // layer 2 + head
    gather2<<<(64 * N_NODES + B - 1) / B, B, 0, stream>>>(row_ptr, pedge, dinv, y2, b2,
                                                         lin_w, lin_b, out);
}